// Round 9
// baseline (735.931 us; speedup 1.0000x reference)
//
#include <hip/hip_runtime.h>
#include <hip/hip_bf16.h>
#include <math.h>

typedef unsigned int uint;
typedef unsigned short ushort;
typedef __attribute__((ext_vector_type(8))) short short8;
typedef __attribute__((ext_vector_type(4))) float f32x4;
typedef __attribute__((ext_vector_type(2))) uint uint2v;

#define SCALE_Q2 (0.18257418583505536f * 1.4426950408889634f)  // 30^-0.5 * log2(e)
#define INV_SCALE_Q 5.477225575051661f        // sqrt(30)

__device__ __forceinline__ ushort f2bf(float f) {
    union { float f; uint i; } v; v.f = f;
    uint i = v.i;
    uint r = (i + 0x7fffu + ((i >> 16) & 1u)) >> 16;
    return (ushort)r;
}

// ---------------------------------------------------------------------------
// Prep: transpose+pad+bf16 weights, pad biases.
// qkv-padded layout downstream: row stride 576, slot = seg*192 + head*32 + d
// ---------------------------------------------------------------------------
__global__ void prep_kernel(const float* __restrict__ qkv_w, const float* __restrict__ qkv_b,
                            const float* __restrict__ proj_w, const float* __restrict__ proj_b,
                            const float* __restrict__ w1, const float* __restrict__ b1,
                            const float* __restrict__ w2, const float* __restrict__ b2,
                            ushort* __restrict__ wq_t, ushort* __restrict__ wp_t,
                            ushort* __restrict__ w1_t, ushort* __restrict__ w2_t,
                            float* __restrict__ bq, float* __restrict__ bp,
                            float* __restrict__ b1p, float* __restrict__ b2p)
{
    int i = blockIdx.x * 256 + threadIdx.x;
    if (i < 576 * 192) { int n = i / 192, k = i % 192;
        wq_t[i] = (n < 540 && k < 180) ? f2bf(qkv_w[k * 540 + n]) : (ushort)0; return; }
    i -= 576 * 192;
    if (i < 192 * 192) { int n = i / 192, k = i % 192;
        int h = k >> 5, d = k & 31;
        wp_t[i] = (n < 180 && d < 30) ? f2bf(proj_w[(h * 30 + d) * 180 + n]) : (ushort)0; return; }
    i -= 192 * 192;
    if (i < 384 * 192) { int n = i / 192, k = i % 192;
        w1_t[i] = (n < 360 && k < 180) ? f2bf(w1[k * 360 + n]) : (ushort)0; return; }
    i -= 384 * 192;
    if (i < 192 * 384) { int n = i / 384, k = i % 384;
        w2_t[i] = (n < 180 && k < 360) ? f2bf(w2[k * 180 + n]) : (ushort)0; return; }
    i -= 192 * 384;
    if (i < 576) { bq[i] = (i < 540) ? qkv_b[i] : 0.f; return; }
    i -= 576;
    if (i < 192) { bp[i] = (i < 180) ? proj_b[i] : 0.f; return; }
    i -= 192;
    if (i < 384) { b1p[i] = (i < 360) ? b1[i] : 0.f; return; }
    i -= 384;
    if (i < 192) { b2p[i] = (i < 180) ? b2[i] : 0.f; return; }
}

// ---------------------------------------------------------------------------
// Bias gather: bias_q[h][q][k] = rpb[rpi[q*576+k]*6+h] * sqrt(30)
// (pre-divided by SCALE_Q so it can enter swapped-QK^T as the MFMA C operand;
//  [q][key] layout matches the S^T C-fragment: 4 consecutive KEYS per lane).
// Both rpi read and bias_q write are k-contiguous (coalesced).
// ---------------------------------------------------------------------------
__global__ void biasprep_kernel(const int* __restrict__ rpi, const float* __restrict__ rpb,
                                float* __restrict__ bias_q)
{
    int i = blockIdx.x * 256 + threadIdx.x;   // 6*256*576 = 884736
    int h = i / 147456;
    int r = i % 147456;                        // q*576 + k
    bias_q[(long)h * 147456 + r] = rpb[rpi[r] * 6 + h] * INV_SCALE_Q;
}

// ---------------------------------------------------------------------------
// LayerNorm: f32 [rows][180] -> bf16 [rows][192]; pad cols 180..191 ZEROED
// ---------------------------------------------------------------------------
__global__ void ln_kernel(const float* __restrict__ x, const float* __restrict__ g,
                          const float* __restrict__ b, ushort* __restrict__ out)
{
    int row = blockIdx.x * 4 + (threadIdx.x >> 6);
    int lane = threadIdx.x & 63;
    const float* xr = x + (long)row * 180;
    float v0 = xr[lane];
    float v1 = xr[lane + 64];
    float v2 = (lane < 52) ? xr[lane + 128] : 0.f;
    float s = v0 + v1 + v2;
    float ss = v0 * v0 + v1 * v1 + v2 * v2;
    #pragma unroll
    for (int m = 1; m < 64; m <<= 1) { s += __shfl_xor(s, m); ss += __shfl_xor(ss, m); }
    float mu = s * (1.f / 180.f);
    float var = ss * (1.f / 180.f) - mu * mu;
    float rs = rsqrtf(var + 1e-5f);
    ushort* orow = out + (long)row * 192;
    orow[lane]      = f2bf((v0 - mu) * rs * g[lane] + b[lane]);
    orow[lane + 64] = f2bf((v1 - mu) * rs * g[lane + 64] + b[lane + 64]);
    orow[lane + 128] = (lane < 52)
        ? f2bf((v2 - mu) * rs * g[lane + 128] + b[lane + 128])
        : (ushort)0;
}

// ---------------------------------------------------------------------------
// GEMM, A-panel-resident: block stages A[MT][KP] in LDS ONCE (XOR-swizzled
// 8-elem granules: LDS[row][g] = A[row][g ^ (row&7)] -> conflict-free b128
// reads), then loops over ALL N tiles; B fragments read straight from global
// (B is <=221KB, L2-resident). No inner-loop barriers.
// EPI 0: bf16 = acc+bias, padded qkv layout (540..575 -> d=30,31 pad slots)
// EPI 1: f32  = acc+bias+aux, stride 180, col<180
// EPI 2: bf16 = gelu(acc+bias), stride 384
// ---------------------------------------------------------------------------
template<int KP, int NT, int MT, int EPI>
__global__ __launch_bounds__(256)
void gemm_kernel(const ushort* __restrict__ A, const ushort* __restrict__ Bt,
                 const float* __restrict__ bias, void* __restrict__ outp,
                 const float* __restrict__ aux)
{
    __shared__ ushort As[MT * KP];
    constexpr int MI = MT / 32;          // m-frags per wave
    constexpr int GR = KP / 8;           // 8-elem granules per row
    const int m0 = blockIdx.x * MT;
    const int tid = threadIdx.x;
    const int lane = tid & 63;
    const int w = tid >> 6;
    const int wr = w >> 1, wc = w & 1;
    const int lg = lane >> 4, lc = lane & 15;

    #pragma unroll
    for (int it = 0; it < MT * GR / 256; ++it) {
        int c = it * 256 + tid;
        int row = c / GR, g = c % GR;
        short8 v = *(const short8*)(A + (long)(m0 + row) * KP + ((g ^ (row & 7)) * 8));
        *(short8*)&As[row * KP + g * 8] = v;
    }
    __syncthreads();

    const int rA = wr * (MT / 2) + lc;
    const int rB = wc * 32 + lc;

    for (int n0 = 0; n0 < NT; n0 += 64) {
        f32x4 acc[MI][2] = {};
        #pragma unroll
        for (int k0 = 0; k0 < KP; k0 += 32) {
            short8 a[MI], bb[2];
            #pragma unroll
            for (int mi = 0; mi < MI; ++mi) {
                int row = rA + mi * 16;
                int g = (k0 / 8 + lg) ^ (row & 7);
                a[mi] = *(const short8*)&As[row * KP + g * 8];
            }
            #pragma unroll
            for (int ni = 0; ni < 2; ++ni)
                bb[ni] = *(const short8*)(Bt + (long)(n0 + rB + ni * 16) * KP + k0 + lg * 8);
            #pragma unroll
            for (int mi = 0; mi < MI; ++mi)
                #pragma unroll
                for (int ni = 0; ni < 2; ++ni)
                    acc[mi][ni] = __builtin_amdgcn_mfma_f32_16x16x32_bf16(
                        a[mi], bb[ni], acc[mi][ni], 0, 0, 0);
        }
        #pragma unroll
        for (int mi = 0; mi < MI; ++mi) {
            #pragma unroll
            for (int ni = 0; ni < 2; ++ni) {
                int col = n0 + wc * 32 + ni * 16 + lc;
                int rbase = m0 + wr * (MT / 2) + mi * 16 + lg * 4;
                float bcol = bias[col];
                #pragma unroll
                for (int r = 0; r < 4; ++r) {
                    long row = rbase + r;
                    float v = acc[mi][ni][r] + bcol;
                    if (EPI == 0) {
                        int seg, hh, dd;
                        if (col < 540) {
                            seg = col / 180; int r2 = col - seg * 180;
                            hh = r2 / 30; dd = r2 - hh * 30;
                        } else {
                            int s2 = col - 540;
                            seg = s2 / 12; int r3 = s2 - seg * 12;
                            hh = r3 >> 1; dd = 30 + (r3 & 1);
                        }
                        ((ushort*)outp)[row * 576 + seg * 192 + hh * 32 + dd] = f2bf(v);
                    } else if (EPI == 1) {
                        if (col < 180)
                            ((float*)outp)[row * 180 + col] = v + aux[row * 180 + col];
                    } else {
                        float t = 0.5f * v * (1.f + erff(v * 0.70710678118654752f));
                        ((ushort*)outp)[row * 384 + col] = f2bf(t);
                    }
                }
            }
        }
    }
}

// ---------------------------------------------------------------------------
// MFMA attention. Block = (window, head), 4 waves, wave owns 64 q rows;
// 9 chunks of 64 keys.
//  - SWAPPED QK^T: S^T = mfma(K, Q, bias^T) -> lane holds 4 consecutive keys
//    per reg quad for ONE q -> P written as 16 ds_write_b64 (was 64 b16)
//  - bias_q[h][q][key] enters as the MFMA C operand (pre-divided by SCALE_Q)
//  - T14 async-stage: chunk ch+1's K/V loads issued right after ch's LDS
//    writes, in flight across QK^T+PV
//  - ones column at Vt d=31 -> PV output col 31 IS the softmax denominator
//  - P/Vt LDS images and the PV step identical to the verified r8 kernel
// ---------------------------------------------------------------------------
__global__ __launch_bounds__(256)
void attn_kernel(const ushort* __restrict__ qkv, const float* __restrict__ bias_q,
                 ushort* __restrict__ obuf)
{
    __shared__ ushort K_lds[64 * 40];
    __shared__ ushort Vt_lds[32 * 64];
    __shared__ ushort P_lds[4][64 * 64];

    const int blk = blockIdx.x;
    const int head = blk % 6;
    const int win = blk / 6;
    const int wj = win & 15, wi = (win >> 4) & 15, b = win >> 8;
    const int t = threadIdx.x;
    const int lane = t & 63;
    const int w = t >> 6;
    const int lg = lane >> 4;      // 0..3
    const int lc = lane & 15;

    // Q as B-operand fragment: col(n)=q by lc, k=d by lg*8+j (same loads as r8)
    short8 qf[4];
    {
        const int x = wj * 16 + lc;
        #pragma unroll
        for (int mi = 0; mi < 4; ++mi) {
            int y = wi * 16 + w * 4 + mi;
            long grow = (long)(b * 256 + y) * 256 + x;
            qf[mi] = *(const short8*)(qkv + grow * 576 + head * 32 + lg * 8);
        }
    }

    ushort* Pw = P_lds[w];
    f32x4 oacc[4][2] = {};
    const short8 zv = {0, 0, 0, 0, 0, 0, 0, 0};

    const int keyloc = t >> 2;   // chunk-local key staged by this thread
    const int p4 = t & 3;        // 16B d-block

    // bias base for swapped C-frag: [q = w*64 + mi*16 + lc][key = ch*64+ni*16+lg*4+r]
    const float* bias_base = bias_q + (long)head * 147456 + (long)(w * 64 + lc) * 576;

    // ---- prologue: load chunk 0 K/V to regs
    short8 kcur, vcur, knxt, vnxt;
    {
        int ky = keyloc / 24, kx = keyloc - ky * 24;
        int gy = wi * 16 - 4 + ky, gx = wj * 16 - 4 + kx;
        bool ok = (gy >= 0 && gy < 256 && gx >= 0 && gx < 256);
        long grow = ok ? ((long)(b * 256 + gy) * 256 + gx) : 0;
        const ushort* base = qkv + grow * 576 + head * 32 + p4 * 8;
        kcur = *(const short8*)(base + 192);
        vcur = *(const short8*)(base + 384);
        if (!ok) { kcur = zv; vcur = zv; }
    }

    for (int ch = 0; ch < 9; ++ch) {
        if (ch) __syncthreads();           // prev PV done reading K/Vt
        // ---- write staged regs to LDS
        *(short8*)&K_lds[keyloc * 40 + p4 * 8] = kcur;
        #pragma unroll
        for (int j = 0; j < 8; ++j) {
            int d = p4 * 8 + j;
            Vt_lds[d * 64 + (keyloc ^ ((d & 7) << 3))] = ((const ushort*)&vcur)[j];
        }
        if (p4 == 3)
            Vt_lds[31 * 64 + (keyloc ^ 56)] = (ushort)0x3F80;   // ones col (denom)

        // ---- issue next chunk's loads (hidden under QK^T + PV)
        if (ch < 8) {
            int kk = (ch + 1) * 64 + keyloc;
            int ky = kk / 24, kx = kk - ky * 24;
            int gy = wi * 16 - 4 + ky, gx = wj * 16 - 4 + kx;
            bool ok = (gy >= 0 && gy < 256 && gx >= 0 && gx < 256);
            long grow = ok ? ((long)(b * 256 + gy) * 256 + gx) : 0;
            const ushort* base = qkv + grow * 576 + head * 32 + p4 * 8;
            knxt = *(const short8*)(base + 192);
            vnxt = *(const short8*)(base + 384);
            if (!ok) { knxt = zv; vnxt = zv; }
        }
        __syncthreads();

        // ---- swapped QK^T: S^T[key][q] = mfma(K, Q, bias^T); P via b64 writes
        short8 kb[4];
        #pragma unroll
        for (int ni = 0; ni < 4; ++ni)
            kb[ni] = *(const short8*)&K_lds[(ni * 16 + lc) * 40 + lg * 8];
        __builtin_amdgcn_s_setprio(1);
        #pragma unroll
        for (int mi = 0; mi < 4; ++mi) {
            int q = mi * 16 + lc;            // wave-local q (fixed per lane)
            int swz = (q & 7) << 3;
            #pragma unroll
            for (int ni = 0; ni < 4; ++ni) {
                int kb0 = ni * 16 + lg * 4;  // first of 4 consecutive keys
                f32x4 bv = *(const f32x4*)(bias_base + mi * 16 * 576
                                           + ch * 64 + kb0);
                f32x4 s = __builtin_amdgcn_mfma_f32_16x16x32_bf16(
                    kb[ni], qf[mi], bv, 0, 0, 0);
                uint b0 = __builtin_bit_cast(uint, exp2f(s[0] * SCALE_Q2));
                uint b1 = __builtin_bit_cast(uint, exp2f(s[1] * SCALE_Q2));
                uint b2 = __builtin_bit_cast(uint, exp2f(s[2] * SCALE_Q2));
                uint b3 = __builtin_bit_cast(uint, exp2f(s[3] * SCALE_Q2));
                uint2v pk;
                pk.x = (b0 >> 16) | (b1 & 0xffff0000u);
                pk.y = (b2 >> 16) | (b3 & 0xffff0000u);
                *(uint2v*)&Pw[q * 64 + (kb0 ^ swz)] = pk;
            }
        }
        __builtin_amdgcn_s_setprio(0);
        __syncthreads();

        // ---- PV: 16 MFMA (identical to r8)
        __builtin_amdgcn_s_setprio(1);
        #pragma unroll
        for (int ks = 0; ks < 2; ++ks) {
            short8 vb[2];
            #pragma unroll
            for (int nj = 0; nj < 2; ++nj) {
                int d = nj * 16 + lc;
                vb[nj] = *(const short8*)&Vt_lds[d * 64
                              + ((ks * 32 + lg * 8) ^ ((d & 7) << 3))];
            }
            #pragma unroll
            for (int mi = 0; mi < 4; ++mi) {
                int q = mi * 16 + lc;
                short8 pa = *(const short8*)&Pw[q * 64
                              + ((ks * 32 + lg * 8) ^ ((q & 7) << 3))];
                #pragma unroll
                for (int nj = 0; nj < 2; ++nj)
                    oacc[mi][nj] = __builtin_amdgcn_mfma_f32_16x16x32_bf16(
                        pa, vb[nj], oacc[mi][nj], 0, 0, 0);
            }
        }
        __builtin_amdgcn_s_setprio(0);
        kcur = knxt; vcur = vnxt;
    }

    // ---- denominator = O[q][31] (lanes lc==15 of nj=1); broadcast + store
    #pragma unroll
    for (int mi = 0; mi < 4; ++mi) {
        int y = wi * 16 + w * 4 + mi;
        #pragma unroll
        for (int r = 0; r < 4; ++r) {
            float denom = __shfl(oacc[mi][1][r], lane | 15);
            float inv = 1.f / denom;
            int x = wj * 16 + lg * 4 + r;
            long grow = (long)(b * 256 + y) * 256 + x;
            #pragma unroll
            for (int nj = 0; nj < 2; ++nj) {
                int d = nj * 16 + lc;
                obuf[grow * 192 + head * 32 + d] = f2bf(d < 30 ? oacc[mi][nj][r] * inv : 0.f);
            }
        }
    }
}

// ---------------------------------------------------------------------------
extern "C" void kernel_launch(void* const* d_in, const int* in_sizes, int n_in,
                              void* d_out, int out_size, void* d_ws, size_t ws_size,
                              hipStream_t stream)
{
    const float* x      = (const float*)d_in[0];
    const int*   rpi    = (const int*)d_in[1];
    const float* qkv_w  = (const float*)d_in[2];
    const float* qkv_b  = (const float*)d_in[3];
    const float* proj_w = (const float*)d_in[4];
    const float* proj_b = (const float*)d_in[5];
    const float* rpb    = (const float*)d_in[6];
    const float* ln1_g  = (const float*)d_in[7];
    const float* ln1_b  = (const float*)d_in[8];
    const float* ln2_g  = (const float*)d_in[9];
    const float* ln2_b  = (const float*)d_in[10];
    const float* w1     = (const float*)d_in[11];
    const float* b1     = (const float*)d_in[12];
    const float* w2     = (const float*)d_in[13];
    const float* b2     = (const float*)d_in[14];
    float* out = (float*)d_out;
    char* ws = (char*)d_ws;

    // ws layout (all 256-aligned)
    ushort* wq_t     = (ushort*)(ws + 0);          // 576*192*2   = 221184
    ushort* wp_t     = (ushort*)(ws + 221184);     // 192*192*2   = 73728
    ushort* w1_t     = (ushort*)(ws + 294912);     // 384*192*2   = 147456
    ushort* w2_t     = (ushort*)(ws + 442368);     // 192*384*2   = 147456
    float*  bq       = (float*)(ws + 589824);      // 576*4
    float*  bp       = (float*)(ws + 592128);      // 192*4
    float*  b1p      = (float*)(ws + 592896);      // 384*4
    float*  b2p      = (float*)(ws + 594432);      // 192*4
    float*  bias_q   = (float*)(ws + 595200);      // 6*256*576*4 = 3538944
    ushort* hbuf     = (ushort*)(ws + 4194304);    // 131072*192*2 = 50331648
    ushort* qkv      = (ushort*)(ws + 54525952);   // 131072*576*2 = 150994944 (padded layout)
    float*  x2f      = (float*)(ws + 54525952);    // overlays qkv after attention
    ushort* obuf     = (ushort*)(ws + 205520896);  // 131072*192*2 = 50331648
    ushort* g1       = (ushort*)(ws + 205520896);  // overlays obuf: 131072*384*2

    prep_kernel<<<1158, 256, 0, stream>>>(qkv_w, qkv_b, proj_w, proj_b,
                                          w1, b1, w2, b2,
                                          wq_t, wp_t, w1_t, w2_t, bq, bp, b1p, b2p);
    biasprep_kernel<<<3456, 256, 0, stream>>>(rpi, rpb, bias_q);
    ln_kernel<<<32768, 256, 0, stream>>>(x, ln1_g, ln1_b, hbuf);
    gemm_kernel<192, 576, 128, 0><<<1024, 256, 0, stream>>>(hbuf, wq_t, bq, qkv, nullptr);
    attn_kernel<<<3072, 256, 0, stream>>>(qkv, bias_q, obuf);
    gemm_kernel<192, 192, 128, 1><<<1024, 256, 0, stream>>>(obuf, wp_t, bp, x2f, x);
    ln_kernel<<<32768, 256, 0, stream>>>(x2f, ln2_g, ln2_b, hbuf);
    gemm_kernel<192, 384, 128, 2><<<1024, 256, 0, stream>>>(hbuf, w1_t, b1p, g1, nullptr);
    gemm_kernel<384, 192, 64, 1><<<2048, 256, 0, stream>>>(g1, w2_t, b2p, out, x2f);
}